// Round 21
// baseline (14733.969 us; speedup 1.0000x reference)
//
#include <hip/hip_runtime.h>
#include <hip/hip_bf16.h>

typedef float f32x4 __attribute__((ext_vector_type(4)));
typedef __bf16 bf16x8 __attribute__((ext_vector_type(8)));

#define B_SZ 2048
#define T_IN 48
#define FEAT 64
#define UNITS 1024
#define GCOLS 4096   // 4*UNITS
#define OUT_STEPS 64
#define KWARM 1088   // UNITS + FEAT

// Gate-major column permutation: c' = 64*Bk + 16*g + u
__device__ __forceinline__ int oc_of(int c) {
    return (((c >> 4) & 3) * UNITS) + ((c >> 6) * 16) + (c & 15);
}

typedef __attribute__((address_space(1))) const void gas_t;
typedef __attribute__((address_space(3))) void las_t;

__device__ __forceinline__ void gl_lds16(const void* g, void* l) {
    __builtin_amdgcn_global_load_lds((gas_t*)g, (las_t*)l, 16, 0, 0);
}
__device__ __forceinline__ float sigm(float x) {
    return __builtin_amdgcn_rcpf(1.0f + __expf(-x));
}
__device__ __forceinline__ float tanh_fast(float x) {
    float e = __expf(2.0f * x);
    return 1.0f - 2.0f * __builtin_amdgcn_rcpf(e + 1.0f);
}

// mb-group barrier (32 blocks sharing h rows), numerically proven in R19.
// Poison (+1<<20 >> max target 32*84) on timeout -> always terminates;
// a residency failure shows as fast absmax fail, never a harness timeout.
__device__ __forceinline__ int group_barrier(int* cnt, int target) {
    __threadfence();                 // release: h stores visible agent-wide
    __syncthreads();
    __shared__ int ok_s;
    if (threadIdx.x == 0) {
        atomicAdd(cnt, 1);
        int ok = 1, spins = 0;
        while (__hip_atomic_load(cnt, __ATOMIC_RELAXED, __HIP_MEMORY_SCOPE_AGENT) < target) {
            __builtin_amdgcn_s_sleep(4);
            if (++spins > (1 << 20)) { ok = 0; atomicAdd(cnt, 1 << 20); break; }
        }
        ok_s = ok;
    }
    __syncthreads();
    __threadfence();                 // acquire: drop stale cached h
    return ok_s;
}

// ---------- precompute kernels (unchanged, correctness-proven) ----------

__global__ __launch_bounds__(256) void reorder_UW(const float* __restrict__ U, const float* __restrict__ W,
                                                  __hip_bfloat16* __restrict__ UTw) {
    __shared__ __hip_bfloat16 t[64][64];
    const int k0 = blockIdx.x * 64;   // 17 tiles
    const int c0 = blockIdx.y * 64;   // 64 tiles
    const int tid = threadIdx.x;
#pragma unroll
    for (int i = 0; i < 16; ++i) {
        int idx = tid + i * 256;
        int rk = idx >> 6, cc = idx & 63;
        int k = k0 + rk, c = c0 + cc;
        int oc = oc_of(c);
        float v = (k < UNITS) ? U[(size_t)k * GCOLS + oc] : W[(size_t)(k - UNITS) * GCOLS + oc];
        t[rk][cc] = __float2bfloat16(v);
    }
    __syncthreads();
#pragma unroll
    for (int i = 0; i < 16; ++i) {
        int idx = tid + i * 256;
        int rc = idx >> 6, kk = idx & 63;
        UTw[(size_t)(c0 + rc) * KWARM + k0 + kk] = t[kk][rc];
    }
}

__global__ __launch_bounds__(256) void transpose_Wd(const float* __restrict__ Wd, __hip_bfloat16* __restrict__ WdT) {
    __shared__ __hip_bfloat16 t[64][64];
    const int k0 = blockIdx.x * 64;  // 16 blocks
    const int tid = threadIdx.x;
#pragma unroll
    for (int i = 0; i < 16; ++i) {
        int idx = tid + i * 256;
        int rk = idx >> 6, ff = idx & 63;
        t[rk][ff] = __float2bfloat16(Wd[(size_t)(k0 + rk) * FEAT + ff]);
    }
    __syncthreads();
#pragma unroll
    for (int i = 0; i < 16; ++i) {
        int idx = tid + i * 256;
        int rf = idx >> 6, kk = idx & 63;
        WdT[(size_t)rf * UNITS + k0 + kk] = t[kk][rf];
    }
}

__global__ __launch_bounds__(256) void build_UTdec(const __hip_bfloat16* __restrict__ UTw,
                                                   const __hip_bfloat16* __restrict__ WdT,
                                                   __hip_bfloat16* __restrict__ UTd) {
    __shared__ float Wl[64][16];
    const int k = blockIdx.x * 256 + threadIdx.x;  // 4 blocks
    const int c0 = blockIdx.y * 16;                // 256 blocks
    const int tid = threadIdx.x;
#pragma unroll
    for (int i = 0; i < 4; ++i) {
        int idx = tid + i * 256;
        int f = idx >> 4, cc = idx & 15;
        Wl[f][cc] = __bfloat162float(UTw[(size_t)(c0 + cc) * KWARM + UNITS + f]);
    }
    __syncthreads();
    float acc[16];
#pragma unroll
    for (int cc = 0; cc < 16; ++cc) acc[cc] = 0.f;
    for (int f = 0; f < 64; ++f) {
        float wd = __bfloat162float(WdT[(size_t)f * UNITS + k]);
#pragma unroll
        for (int cc = 0; cc < 16; ++cc) acc[cc] += wd * Wl[f][cc];
    }
#pragma unroll
    for (int cc = 0; cc < 16; ++cc) {
        float uv = __bfloat162float(UTw[(size_t)(c0 + cc) * KWARM + k]);
        UTd[(size_t)(c0 + cc) * UNITS + k] = __float2bfloat16(uv + acc[cc]);
    }
}

__global__ __launch_bounds__(256) void build_bias(const float* __restrict__ b, const float* __restrict__ bd,
                                                  const __hip_bfloat16* __restrict__ UTw,
                                                  float* __restrict__ bw, float* __restrict__ bdc) {
    const int c = blockIdx.x * 256 + threadIdx.x;  // 16 blocks
    const int oc = oc_of(c);
    float base = b[oc];
    float s = 0.f;
    for (int f = 0; f < FEAT; ++f) s += bd[f] * __bfloat162float(UTw[(size_t)c * KWARM + UNITS + f]);
    bw[c] = base;
    bdc[c] = base + s;
}

__global__ void convert_x(const float* __restrict__ x, __hip_bfloat16* __restrict__ xb, int n) {
    int i = blockIdx.x * blockDim.x + threadIdx.x;
    if (i < n) xb[i] = __float2bfloat16(x[i]);
}

// ---------- fused LSTM: FOUR steps per dispatch ----------
// R21 = R20's proven per-step body (128x128 tile, BK=64 gl_lds dbuf, counted
// vmcnt, swizzle, 8x8-per-XCD rectangle, bf16 c) run 4x per dispatch with
// mb-group barriers between steps. Rationale: R20 falsified bandwidth-bound
// (traffic -15% -> time 0%); dispatches are pinned ~64us regardless of bytes
// -> per-dispatch fixed cost dominates. h deps are mb-local (32 blocks), so
// group sync suffices (R19 proved it numerically). 112 -> 28 dispatches.
// Even step count per dispatch => every dispatch reads hA first, ends on hA.
template <bool WARM, bool PRED>
__global__ __launch_bounds__(256) void lstm_step4(
    __hip_bfloat16* __restrict__ hA,                 // [2048][1024]
    __hip_bfloat16* __restrict__ hB,                 // [2048][1024]
    const __hip_bfloat16* __restrict__ xbf, int t0,  // (WARM) first x index
    const __hip_bfloat16* __restrict__ UT,           // [4096][KD]
    const float* __restrict__ bias,                  // [4096]
    __hip_bfloat16* __restrict__ cst,                // [2048][1024] bf16
    const __hip_bfloat16* __restrict__ WdT,          // [64][1024] (PRED)
    const float* __restrict__ bd,                    // [64] (PRED)
    float* __restrict__ out, int tstep0,             // (PRED) first pred index
    int* __restrict__ sync_cnt, int sbase)           // 16x32-int counters; barriers done before
{
    constexpr int KD = WARM ? KWARM : UNITS;
    constexpr int NKT = KD / 64;

    __shared__ alignas(16) __hip_bfloat16 Al[2 * 8192];   // 32 KB
    __shared__ alignas(16) __hip_bfloat16 Bl[2 * 8192];   // 32 KB

    const int tid = threadIdx.x;
    const int lane = tid & 63;
    const int wv = tid >> 6;
    const int wr = wv >> 1, wc = wv & 1;
    const int bid = blockIdx.x;
    // 8mb x 8nb rectangle per XCD: A-slice 2MB + B-slice 2MB fits the 4MB L2.
    const int x = bid & 7;
    const int i6 = bid >> 3;
    const int mb = ((x >> 2) << 3) + (i6 >> 3);   // 0..15
    const int nb = ((x & 3) << 3) + (i6 & 7);     // 0..31
    const int m0 = mb * 128;
    const int n0 = nb * 128;
    const bool doPred = PRED && (nb < 4);
    int* grp = sync_cnt + mb * 32;

    const int lrow = lane >> 3;
    const int scol = ((lane & 7) * 16) ^ (lrow << 4);   // swizzled source byte col

    // loop-invariant offsets/bases
    size_t aOff[4]; const char* bS[4]; const char* xB[4];
#pragma unroll
    for (int r = 0; r < 4; ++r) {
        int row = (r * 4 + wv) * 8 + lrow;
        aOff[r] = (size_t)(m0 + row) * (UNITS * 2) + scol;
        bS[r] = (const char*)UT + (size_t)(n0 + row) * (KD * 2) + scol;
        if (WARM) xB[r] = (const char*)xbf + (size_t)(m0 + row) * (T_IN * FEAT * 2) + scol;
    }

    const int ar = lane & 15;
    const int ko = (lane >> 4) << 3;
    const int swz = (ar & 7) << 3;

    const char* wB = nullptr;
    if (PRED && doPred)
        wB = (const char*)WdT + ((size_t)(16 * nb + ar) * UNITS + ko) * 2;

    // epilogue geometry; biases fixed across the 4 steps
    const int u16 = lane & 15;
    const int unit = (nb * 2 + wc) * 16 + u16;
    const int rbase = m0 + 64 * wr + ((lane >> 4) << 2);
    float bv[4];
#pragma unroll
    for (int g = 0; g < 4; ++g) bv[g] = bias[n0 + 64 * wc + 16 * g + u16];
    float bdv = 0.f;
    if (PRED && doPred) bdv = bd[16 * nb + u16];

    int healthy = 1;

#pragma unroll 1
    for (int j = 0; j < 4; ++j) {
        const char* hin = (const char*)((j & 1) ? hB : hA);
        __hip_bfloat16* hout = (j & 1) ? hA : hB;
        const char* aS[4];
#pragma unroll
        for (int r = 0; r < 4; ++r) aS[r] = hin + aOff[r];
        const int xoff = WARM ? (t0 + j) * (FEAT * 2) : 0;

        f32x4 acc[4][4] = {};
        f32x4 accp[2] = {};
        bf16x8 Wf[2][2];

        auto stage = [&](int kt) {
            const int buf = kt & 1;
#pragma unroll
            for (int r = 0; r < 4; ++r) {
                const char* s = (WARM && kt == NKT - 1) ? (xB[r] + xoff) : (aS[r] + kt * 128);
                gl_lds16(s, (char*)Al + buf * 16384 + (r * 4 + wv) * 1024);
            }
#pragma unroll
            for (int r = 0; r < 4; ++r)
                gl_lds16(bS[r] + kt * 128, (char*)Bl + buf * 16384 + (r * 4 + wv) * 1024);
        };
        auto loadWf = [&](int kt) {
            if (PRED && doPred) {
#pragma unroll
                for (int kk = 0; kk < 2; ++kk)
                    Wf[kt & 1][kk] = *reinterpret_cast<const bf16x8*>(wB + kt * 128 + kk * 64);
            }
        };
        auto compute = [&](int kt) {
            const int buf = kt & 1;
#pragma unroll
            for (int kk = 0; kk < 2; ++kk) {
                bf16x8 af[4], bfr[4];
#pragma unroll
                for (int mi = 0; mi < 4; ++mi)
                    af[mi] = *reinterpret_cast<const bf16x8*>(&Al[buf * 8192 + (64 * wr + 16 * mi + ar) * 64 + ((32 * kk + ko) ^ swz)]);
#pragma unroll
                for (int ni = 0; ni < 4; ++ni)
                    bfr[ni] = *reinterpret_cast<const bf16x8*>(&Bl[buf * 8192 + (64 * wc + 16 * ni + ar) * 64 + ((32 * kk + ko) ^ swz)]);
#pragma unroll
                for (int mi = 0; mi < 4; ++mi)
#pragma unroll
                    for (int ni = 0; ni < 4; ++ni)
                        acc[mi][ni] = __builtin_amdgcn_mfma_f32_16x16x32_bf16(af[mi], bfr[ni], acc[mi][ni], 0, 0, 0);
                if (PRED && doPred) {
#pragma unroll
                    for (int pi = 0; pi < 2; ++pi)
                        accp[pi] = __builtin_amdgcn_mfma_f32_16x16x32_bf16(af[2 * wc + pi], Wf[kt & 1][kk], accp[pi], 0, 0, 0);
                }
            }
        };

        // ---- pipelined K loop (counts identical to R20 for all j) ----
        stage(0);
        loadWf(0);
#pragma unroll
        for (int kt = 0; kt < NKT - 1; ++kt) {
            stage(kt + 1);
            loadWf(kt + 1);
            if (PRED && doPred) asm volatile("s_waitcnt vmcnt(10) lgkmcnt(0)" ::: "memory");
            else                asm volatile("s_waitcnt vmcnt(8) lgkmcnt(0)" ::: "memory");
            __builtin_amdgcn_s_barrier();
            compute(kt);
            __builtin_amdgcn_s_barrier();
        }
        // prefetch c-state (bf16) under the final MFMA phase
        float cv[16];
#pragma unroll
        for (int mi = 0; mi < 4; ++mi)
#pragma unroll
            for (int reg = 0; reg < 4; ++reg)
                cv[mi * 4 + reg] = __bfloat162float(cst[(size_t)(rbase + 16 * mi + reg) * UNITS + unit]);
        asm volatile("s_waitcnt vmcnt(16) lgkmcnt(0)" ::: "memory");
        __builtin_amdgcn_s_barrier();
        compute(NKT - 1);

        // ---- gate epilogue ----
#pragma unroll
        for (int mi = 0; mi < 4; ++mi)
#pragma unroll
            for (int reg = 0; reg < 4; ++reg) {
                float zi = acc[mi][0][reg] + bv[0];
                float zf = acc[mi][1][reg] + bv[1];
                float zg = acc[mi][2][reg] + bv[2];
                float zo = acc[mi][3][reg] + bv[3];
                float cn = sigm(zf) * cv[mi * 4 + reg] + sigm(zi) * tanh_fast(zg);
                size_t idx = (size_t)(rbase + 16 * mi + reg) * UNITS + unit;
                cst[idx] = __float2bfloat16(cn);
                hout[idx] = __float2bfloat16(sigm(zo) * tanh_fast(cn));
            }

        if (PRED && doPred) {
            const int tstep = tstep0 + j;
#pragma unroll
            for (int pi = 0; pi < 2; ++pi) {
                const int prow = m0 + 64 * wr + 32 * wc + 16 * pi + ((lane >> 4) << 2);
                f32x4 v = accp[pi];
#pragma unroll
                for (int reg = 0; reg < 4; ++reg)
                    out[(size_t)(prow + reg) * (OUT_STEPS * FEAT) + (size_t)tstep * FEAT + (16 * nb + u16)] = v[reg] + bdv;
            }
        }

        // mb-group barrier between steps (not after the last: dispatch boundary)
        if (j < 3 && healthy)
            healthy = group_barrier(grp, 32 * (sbase + j + 1));
    }
}

// ---------- host ----------
extern "C" void kernel_launch(void* const* d_in, const int* in_sizes, int n_in,
                              void* d_out, int out_size, void* d_ws, size_t ws_size,
                              hipStream_t stream) {
    const float* inputs = (const float*)d_in[0];
    const float* W  = (const float*)d_in[1];
    const float* U  = (const float*)d_in[2];
    const float* b  = (const float*)d_in[3];
    const float* Wd = (const float*)d_in[4];
    const float* bd = (const float*)d_in[5];
    float* out = (float*)d_out;

    char* ws = (char*)d_ws;
    size_t off = 0;
    auto alloc = [&](size_t bytes) { char* p = ws + off; off = (off + bytes + 255) & ~255ULL; return p; };
    __hip_bfloat16* UTw = (__hip_bfloat16*)alloc((size_t)GCOLS * KWARM * 2);
    __hip_bfloat16* UTd = (__hip_bfloat16*)alloc((size_t)GCOLS * UNITS * 2);
    __hip_bfloat16* WdT = (__hip_bfloat16*)alloc((size_t)FEAT * UNITS * 2);
    __hip_bfloat16* Xbf = (__hip_bfloat16*)alloc((size_t)B_SZ * T_IN * FEAT * 2);
    __hip_bfloat16* hA  = (__hip_bfloat16*)alloc((size_t)B_SZ * UNITS * 2);
    __hip_bfloat16* hB  = (__hip_bfloat16*)alloc((size_t)B_SZ * UNITS * 2);
    __hip_bfloat16* cst = (__hip_bfloat16*)alloc((size_t)B_SZ * UNITS * 2);
    float* bw  = (float*)alloc(GCOLS * 4);
    float* bdc = (float*)alloc(GCOLS * 4);
    int* sync_cnt = (int*)alloc(4096);

    hipMemsetAsync(cst, 0, (size_t)B_SZ * UNITS * 2, stream);
    hipMemsetAsync(hA, 0, (size_t)B_SZ * UNITS * 2, stream);
    hipMemsetAsync(sync_cnt, 0, 4096, stream);

    dim3 blk(256);
    reorder_UW<<<dim3(17, 64), blk, 0, stream>>>(U, W, UTw);
    transpose_Wd<<<dim3(16), blk, 0, stream>>>(Wd, WdT);
    build_UTdec<<<dim3(4, 256), blk, 0, stream>>>(UTw, WdT, UTd);
    build_bias<<<dim3(16), blk, 0, stream>>>(b, bd, UTw, bw, bdc);
    {
        int n = B_SZ * T_IN * FEAT;
        convert_x<<<dim3((n + 255) / 256), blk, 0, stream>>>(inputs, Xbf, n);
    }

    // 12 warm dispatches x 4 steps (each starts reading hA, ends writing hA)
    for (int d = 0; d < 12; ++d) {
        lstm_step4<true, false><<<dim3(512), blk, 0, stream>>>(
            hA, hB, Xbf, 4 * d, UTw, bw, cst, nullptr, nullptr, nullptr, 0,
            sync_cnt, 3 * d);
    }
    // 16 decode dispatches x 4 steps; step j writes pred (tstep0+j)
    for (int d = 0; d < 16; ++d) {
        lstm_step4<false, true><<<dim3(512), blk, 0, stream>>>(
            hA, hB, nullptr, 0, UTd, bdc, cst, WdT, bd, out, 4 * d,
            sync_cnt, 3 * (12 + d));
    }
}